// Round 4
// baseline (704.588 us; speedup 1.0000x reference)
//
#include <hip/hip_runtime.h>
#include <math.h>

#define DEV __device__ __forceinline__

DEV float gelu_exact(float v) {
    return 0.5f * v * (1.0f + erff(v * 0.7071067811865476f));
}

typedef __attribute__((ext_vector_type(8))) short bf16x8;
typedef __attribute__((ext_vector_type(4))) float f32x4;

DEV short f2b(float f) {
    unsigned u = __builtin_bit_cast(unsigned, f);
    unsigned r = (u + 0x7fffu + ((u >> 16) & 1u)) >> 16;
    return (short)r;
}

// LDS row permute: spreads pt's x-bits into low address bits so both the
// b128 frag reads (verified: 8 starts spaced 4, 2 lanes each = floor) and
// the b32 conv writes (8-way, ~2% of phase-1) behave.  Bijective on [0,256).
DEV int rmap(int pt) { return pt ^ ((pt >> 2) & 7); }

// ---------------------------------------------------------------------------
// K1: tiny MLPs -> conv weights sw[96][125] (f32) and transposed mix matrix
// Mtt[gw=96][fv=96] in bf16 (so fk's A-frags are single 16B vector loads).
// ---------------------------------------------------------------------------
__global__ __launch_bounds__(256) void wk(
    const float* __restrict__ spatial, const float* __restrict__ spherical,
    const float* __restrict__ bw1, const float* __restrict__ bb1,
    const float* __restrict__ bw2, const float* __restrict__ bb2,
    const float* __restrict__ bw3,
    const float* __restrict__ fw1, const float* __restrict__ fb1,
    const float* __restrict__ fw2, const float* __restrict__ fb2,
    const float* __restrict__ fw3,
    float* __restrict__ sw, unsigned short* __restrict__ Mtt) {
    const int i = blockIdx.x * 256 + threadIdx.x;
    if (i < 1500) {
        const float a = spatial[2 * i], b = spatial[2 * i + 1];
        float ft[14];
        ft[0] = a; ft[1] = b;
        ft[2] = a * a; ft[3] = a * b; ft[4] = b * a; ft[5] = b * b;
#pragma unroll
        for (int k = 0; k < 4; ++k) {
            ft[6 + 2 * k] = ft[2 + k] * a;
            ft[7 + 2 * k] = ft[2 + k] * b;
        }
        float h1[8], h2[8];
#pragma unroll
        for (int j = 0; j < 8; ++j) {
            float s = bb1[j];
#pragma unroll
            for (int k = 0; k < 14; ++k) s = fmaf(bw1[j * 14 + k], ft[k], s);
            h1[j] = gelu_exact(s);
        }
#pragma unroll
        for (int j = 0; j < 8; ++j) {
            float s = bb2[j];
#pragma unroll
            for (int k = 0; k < 8; ++k) s = fmaf(bw2[j * 8 + k], h1[k], s);
            h2[j] = gelu_exact(s);
        }
        const int o = i / 12, v = i % 12;
#pragma unroll
        for (int c = 0; c < 8; ++c) {
            float s = 0.f;
#pragma unroll
            for (int k = 0; k < 8; ++k) s = fmaf(bw3[c * 8 + k], h2[k], s);
            sw[(c * 12 + v) * 125 + o] = s;   // channel ch = cin*12+v, tap o = A*25+B*5+C
        }
    } else if (i < 1644) {
        const int r = i - 1500;
        const float s0 = spherical[r];
        float ft[3];
        ft[0] = s0; ft[1] = s0 * s0; ft[2] = s0 * s0 * s0;
        float h1[8], h2[8];
#pragma unroll
        for (int j = 0; j < 8; ++j) {
            float s = fb1[j];
#pragma unroll
            for (int k = 0; k < 3; ++k) s = fmaf(fw1[j * 3 + k], ft[k], s);
            h1[j] = gelu_exact(s);
        }
#pragma unroll
        for (int j = 0; j < 8; ++j) {
            float s = fb2[j];
#pragma unroll
            for (int k = 0; k < 8; ++k) s = fmaf(fw2[j * 8 + k], h1[k], s);
            h2[j] = gelu_exact(s);
        }
        const int v = r / 12, w = r % 12;     // spherical row = (v, w)
#pragma unroll
        for (int c = 0; c < 64; ++c) {        // c = f*8 + g
            float s = 0.f;
#pragma unroll
            for (int k = 0; k < 8; ++k) s = fmaf(fw3[c * 8 + k], h2[k], s);
            const int f = c >> 3, g = c & 7;
            Mtt[(g * 12 + w) * 96 + f * 12 + v] = (unsigned short)f2b(s);
        }
    }
}

// ---------------------------------------------------------------------------
// FUSED kernel: depthwise 5x5x5 conv + 96->96 MFMA mix + bias, one pass.
// Block = (batch b, spatial tile 64x x 2y x 2z = 256 pts), all 96 channels.
// Phase 1: wave wv convolves channels [wv*24, wv*24+24) (wave-uniform ->
//   scalar weights); thread (g = lane>>4 -> (zg,yg), xq = lane&15 -> 4 x's)
//   produces 4 outputs/channel via round-0 shuffle-halo; results packed as
//   bf16 channel-pairs into LDS yt[rmap(pt)][96] (pitch 104 ushorts).
// Phase 2: ek's verified MFMA mix; B-frags are b128 LDS reads (bank floor),
//   A-frags 16B loads of Mtt; D written directly to out (4x64B per instr).
// Numerics identical to the ck->ek pipeline (same f2b at the same place).
// ---------------------------------------------------------------------------
__global__ __launch_bounds__(256) void fk(const float* __restrict__ x,
                                          const float* __restrict__ sw,
                                          const unsigned short* __restrict__ Mtt,
                                          const float* __restrict__ bias,
                                          float* __restrict__ out) {
    __shared__ __align__(16) unsigned short yt[256 * 104];   // 53248 B
    const int t = threadIdx.x;
    const int b = blockIdx.y;
    // 2x2 chunk swizzle over the 32x32 grid of (ytile, ztile) for L2 halo reuse
    const int bx = blockIdx.x;
    const int cid = bx >> 2;
    const int yti = ((cid & 15) << 1) | (bx & 1);
    const int zti = ((cid >> 4) << 1) | ((bx >> 1) & 1);
    const int ty = yti << 1, tz = zti << 1;

    const int xq = t & 15;
    const int g = (t >> 4) & 3;            // (zg,yg) line within tile
    const int zg = g >> 1, yg = g & 1;
    const int wvu = __builtin_amdgcn_readfirstlane(t >> 6);  // wave id (SGPR)

    // ---- per-row clamped offsets + validity bitmask (25 rows, reused 24x) --
    int off[25];
    unsigned vm = 0;
#pragma unroll
    for (int r = 0; r < 25; ++r) {
        const int hz = r / 5, hy = r % 5;
        const int zz = tz + zg + hz - 2;
        const int yy = ty + yg + hy - 2;
        const int zc = min(max(zz, 0), 63), yc = min(max(yy, 0), 63);
        off[r] = (zc << 12) + (yc << 6) + (xq << 2);
        if ((unsigned)zz < 64u && (unsigned)yy < 64u) vm |= (1u << r);
    }

    // ---- phase 1: conv 24 channels, pack ch-pairs into yt ------------------
    unsigned* const ytw = (unsigned*)yt;
#pragma unroll 1
    for (int itp = 0; itp < 12; ++itp) {
        unsigned pk[4];
#pragma unroll
        for (int c2 = 0; c2 < 2; ++c2) {
            const int ch = wvu * 24 + itp * 2 + c2;       // wave-uniform
            const float* __restrict__ xb = x + ((long)(b * 96 + ch) << 18);
            const float* __restrict__ w = sw + ch * 125;  // scalar loads
            float acc[4] = {0.f, 0.f, 0.f, 0.f};
#pragma unroll
            for (int r = 0; r < 25; ++r) {
                float4 v4 = *(const float4*)(xb + off[r]);
                const bool ok = (vm >> r) & 1u;           // per-g uniform
                v4.x = ok ? v4.x : 0.f;
                v4.y = ok ? v4.y : 0.f;
                v4.z = ok ? v4.z : 0.f;
                v4.w = ok ? v4.w : 0.f;
                const float uz = __shfl_up(v4.z, 1, 16);
                const float uw = __shfl_up(v4.w, 1, 16);
                const float dx_ = __shfl_down(v4.x, 1, 16);
                const float dy_ = __shfl_down(v4.y, 1, 16);
                float f[8];
                f[0] = (xq > 0) ? uz : 0.f;
                f[1] = (xq > 0) ? uw : 0.f;
                f[2] = v4.x; f[3] = v4.y; f[4] = v4.z; f[5] = v4.w;
                f[6] = (xq < 15) ? dx_ : 0.f;
                f[7] = (xq < 15) ? dy_ : 0.f;
                const float* wr = w + r * 5;
#pragma unroll
                for (int C = 0; C < 5; ++C) {
                    const float wv_ = wr[C];
#pragma unroll
                    for (int dx = 0; dx < 4; ++dx)
                        acc[dx] = fmaf(f[C + dx], wv_, acc[dx]);
                }
            }
#pragma unroll
            for (int dx = 0; dx < 4; ++dx) {
                const unsigned h = (unsigned short)f2b(acc[dx]);
                if (c2 == 0) pk[dx] = h;
                else         pk[dx] |= (h << 16);
            }
        }
        const int col = wvu * 12 + itp;                   // dword column
#pragma unroll
        for (int dx = 0; dx < 4; ++dx) {
            const int pt = (g << 6) + (xq << 2) + dx;
            ytw[rmap(pt) * 52 + col] = pk[dx];
        }
    }
    __syncthreads();

    // ---- phase 2: MFMA mix (verified ek structure) -------------------------
    const int lane = t & 63;
    const int l15 = lane & 15, quad = lane >> 4;

    // B-frags: wave wvu owns line zy=wvu (64 pts = 4 n-tiles of 16)
    bf16x8 Bf[4][3];
#pragma unroll
    for (int kk = 0; kk < 4; ++kk)
#pragma unroll
        for (int ks = 0; ks < 3; ++ks) {
            const int pt = (wvu << 6) + (kk << 4) + l15;
            Bf[kk][ks] = *(const bf16x8*)(yt + rmap(pt) * 104 + ks * 32 + quad * 8);
        }

    const long ob = ((long)b * 96) << 18;
    const int ptg0 = ((tz + (wvu >> 1)) << 12) + ((ty + (wvu & 1)) << 6);
#pragma unroll
    for (int mt = 0; mt < 6; ++mt) {
        bf16x8 Af[3];
#pragma unroll
        for (int ks = 0; ks < 3; ++ks)
            Af[ks] = *(const bf16x8*)(Mtt + (mt * 16 + l15) * 96 + ks * 32 + quad * 8);
#pragma unroll
        for (int kk = 0; kk < 4; ++kk) {
            f32x4 c = {0.f, 0.f, 0.f, 0.f};
#pragma unroll
            for (int ks = 0; ks < 3; ++ks)
                c = __builtin_amdgcn_mfma_f32_16x16x32_bf16(Af[ks], Bf[kk][ks], c, 0, 0, 0);
#pragma unroll
            for (int r = 0; r < 4; ++r) {
                const int gw = mt * 16 + quad * 4 + r;
                out[ob + ((long)gw << 18) + ptg0 + (kk << 4) + l15] = c[r] + bias[gw / 12];
            }
        }
    }
}

// ---------------------------------------------------------------------------
extern "C" void kernel_launch(void* const* d_in, const int* in_sizes, int n_in,
                              void* d_out, int out_size, void* d_ws, size_t ws_size,
                              hipStream_t stream) {
    const float* x        = (const float*)d_in[0];
    const float* spatial  = (const float*)d_in[1];
    const float* spherical= (const float*)d_in[2];
    const float* bw1 = (const float*)d_in[3];
    const float* bb1 = (const float*)d_in[4];
    const float* bw2 = (const float*)d_in[5];
    const float* bb2 = (const float*)d_in[6];
    const float* bw3 = (const float*)d_in[7];
    const float* fw1 = (const float*)d_in[8];
    const float* fb1 = (const float*)d_in[9];
    const float* fw2 = (const float*)d_in[10];
    const float* fb2 = (const float*)d_in[11];
    const float* fw3 = (const float*)d_in[12];
    const float* bias = (const float*)d_in[13];

    float* sw = (float*)d_ws;                                     // 12000 floats
    unsigned short* Mtt = (unsigned short*)((char*)d_ws + 48128); // 9216 bf16
    float* out = (float*)d_out;

    hipLaunchKernelGGL(wk, dim3(7), dim3(256), 0, stream,
                       spatial, spherical, bw1, bb1, bw2, bb2, bw3,
                       fw1, fb1, fw2, fb2, fw3, sw, Mtt);
    hipLaunchKernelGGL(fk, dim3(1024, 2), dim3(256), 0, stream,
                       x, sw, Mtt, bias, out);
    (void)in_sizes; (void)n_in; (void)out_size; (void)ws_size;
}

// Round 5
// 559.848 us; speedup vs baseline: 1.2585x; 1.2585x over previous
//
#include <hip/hip_runtime.h>
#include <math.h>

#define DEV __device__ __forceinline__

DEV float gelu_exact(float v) {
    return 0.5f * v * (1.0f + erff(v * 0.7071067811865476f));
}

typedef __attribute__((ext_vector_type(8))) short bf16x8;
typedef __attribute__((ext_vector_type(4))) float f32x4;

DEV short f2b(float f) {
    unsigned u = __builtin_bit_cast(unsigned, f);
    unsigned r = (u + 0x7fffu + ((u >> 16) & 1u)) >> 16;
    return (short)r;
}

// ---------------------------------------------------------------------------
// K1: tiny MLPs -> conv weights sw[96][125] (f32) and transposed mix matrix
// Mtt[gw=96][fv=96] in bf16 (so ek's A-frags are single 16B vector loads).
// ---------------------------------------------------------------------------
__global__ __launch_bounds__(256) void wk(
    const float* __restrict__ spatial, const float* __restrict__ spherical,
    const float* __restrict__ bw1, const float* __restrict__ bb1,
    const float* __restrict__ bw2, const float* __restrict__ bb2,
    const float* __restrict__ bw3,
    const float* __restrict__ fw1, const float* __restrict__ fb1,
    const float* __restrict__ fw2, const float* __restrict__ fb2,
    const float* __restrict__ fw3,
    float* __restrict__ sw, unsigned short* __restrict__ Mtt) {
    const int i = blockIdx.x * 256 + threadIdx.x;
    if (i < 1500) {
        const float a = spatial[2 * i], b = spatial[2 * i + 1];
        float ft[14];
        ft[0] = a; ft[1] = b;
        ft[2] = a * a; ft[3] = a * b; ft[4] = b * a; ft[5] = b * b;
#pragma unroll
        for (int k = 0; k < 4; ++k) {
            ft[6 + 2 * k] = ft[2 + k] * a;
            ft[7 + 2 * k] = ft[2 + k] * b;
        }
        float h1[8], h2[8];
#pragma unroll
        for (int j = 0; j < 8; ++j) {
            float s = bb1[j];
#pragma unroll
            for (int k = 0; k < 14; ++k) s = fmaf(bw1[j * 14 + k], ft[k], s);
            h1[j] = gelu_exact(s);
        }
#pragma unroll
        for (int j = 0; j < 8; ++j) {
            float s = bb2[j];
#pragma unroll
            for (int k = 0; k < 8; ++k) s = fmaf(bw2[j * 8 + k], h1[k], s);
            h2[j] = gelu_exact(s);
        }
        const int o = i / 12, v = i % 12;
#pragma unroll
        for (int c = 0; c < 8; ++c) {
            float s = 0.f;
#pragma unroll
            for (int k = 0; k < 8; ++k) s = fmaf(bw3[c * 8 + k], h2[k], s);
            sw[(c * 12 + v) * 125 + o] = s;   // channel ch = cin*12+v, tap o = A*25+B*5+C
        }
    } else if (i < 1644) {
        const int r = i - 1500;
        const float s0 = spherical[r];
        float ft[3];
        ft[0] = s0; ft[1] = s0 * s0; ft[2] = s0 * s0 * s0;
        float h1[8], h2[8];
#pragma unroll
        for (int j = 0; j < 8; ++j) {
            float s = fb1[j];
#pragma unroll
            for (int k = 0; k < 3; ++k) s = fmaf(fw1[j * 3 + k], ft[k], s);
            h1[j] = gelu_exact(s);
        }
#pragma unroll
        for (int j = 0; j < 8; ++j) {
            float s = fb2[j];
#pragma unroll
            for (int k = 0; k < 8; ++k) s = fmaf(fw2[j * 8 + k], h1[k], s);
            h2[j] = gelu_exact(s);
        }
        const int v = r / 12, w = r % 12;     // spherical row = (v, w)
#pragma unroll
        for (int c = 0; c < 64; ++c) {        // c = f*8 + g
            float s = 0.f;
#pragma unroll
            for (int k = 0; k < 8; ++k) s = fmaf(fw3[c * 8 + k], h2[k], s);
            const int f = c >> 3, g = c & 7;
            Mtt[(g * 12 + w) * 96 + f * 12 + v] = (unsigned short)f2b(s);
        }
    }
}

// ---------------------------------------------------------------------------
// K2: depthwise 5x5x5 conv, SAME/zero pad.  One block = 1 (b, channel PAIR),
// tile 64x x 8y x 16z.  Thread tile 8x * 2y * 2z = 32 outputs/channel:
// per 36 row-iterations we now do 4000 FMA/channel (111 FMA/row), halving
// the load/shfl/setup overhead per FMA vs the 4x tile and doubling acc ILP.
// Halo in x from neighbor lanes via shfl within 8-lane groups (all branches
// group-uniform).  Results packed as bf16 ch-pairs {lo=even ch, hi=odd ch}
// into rows [0..48) of the out buffer (identical layout/numerics to R3).
// ---------------------------------------------------------------------------
__global__ __launch_bounds__(256) void ck(const float* __restrict__ x,
                                          const float* __restrict__ sw,
                                          unsigned int* __restrict__ yp) {
    const int chp = blockIdx.y, b = blockIdx.z;
    const int ty = (blockIdx.x & 7) << 3;
    const int tz = (blockIdx.x >> 3) << 4;
    const int t = threadIdx.x;
    const int xq = t & 7;
    const int x0 = xq << 3;
    const int y0 = ty + (((t >> 3) & 3) << 1);
    const int z0 = tz + ((t >> 5) << 1);

    unsigned pk[2][2][8];
#pragma unroll
    for (int i = 0; i < 2; ++i)
#pragma unroll
        for (int j = 0; j < 2; ++j)
#pragma unroll
            for (int k = 0; k < 8; ++k) pk[i][j][k] = 0u;

    // channel order: odd first, then even -> pk = (odd<<16)|even after shift-or
#pragma unroll 1
    for (int c2i = 0; c2i < 2; ++c2i) {
        const int ch = chp * 2 + 1 - c2i;             // wave-uniform (SGPR)
        const float* __restrict__ xb = x + ((long)(b * 96 + ch) << 18);
        const float* __restrict__ w = sw + ch * 125;  // uniform -> scalar loads

        float acc[2][2][8];
#pragma unroll
        for (int i = 0; i < 2; ++i)
#pragma unroll
            for (int j = 0; j < 2; ++j)
#pragma unroll
                for (int k = 0; k < 8; ++k) acc[i][j][k] = 0.f;

#pragma unroll
        for (int hz = 0; hz < 6; ++hz) {
            const int zz = z0 + hz - 2;
            if (zz < 0 || zz >= 64) continue;   // uniform within 32-lane half
#pragma unroll
            for (int hy = 0; hy < 6; ++hy) {
                const int yy = y0 + hy - 2;
                // yy uniform within each 8-lane shuffle group.
                if (yy >= 0 && yy < 64) {
                    const float* row = xb + (zz << 12) + (yy << 6) + x0;
                    const float4 va = *(const float4*)row;
                    const float4 vb = *(const float4*)(row + 4);
                    const float u0 = __shfl_up(vb.z, 1, 8);
                    const float u1 = __shfl_up(vb.w, 1, 8);
                    const float d0 = __shfl_down(va.x, 1, 8);
                    const float d1 = __shfl_down(va.y, 1, 8);
                    float f[12];
                    f[0] = (xq > 0) ? u0 : 0.f;
                    f[1] = (xq > 0) ? u1 : 0.f;
                    f[2] = va.x; f[3] = va.y; f[4] = va.z; f[5] = va.w;
                    f[6] = vb.x; f[7] = vb.y; f[8] = vb.z; f[9] = vb.w;
                    f[10] = (xq < 7) ? d0 : 0.f;
                    f[11] = (xq < 7) ? d1 : 0.f;
#pragma unroll
                    for (int dz = 0; dz < 2; ++dz) {
                        const int A = hz - dz;
                        if (A < 0 || A > 4) continue;   // folded at compile time
#pragma unroll
                        for (int dy = 0; dy < 2; ++dy) {
                            const int B = hy - dy;
                            if (B < 0 || B > 4) continue;
                            const float* wr = w + (A * 5 + B) * 5;
#pragma unroll
                            for (int C = 0; C < 5; ++C) {
                                const float wv = wr[C];
#pragma unroll
                                for (int dx = 0; dx < 8; ++dx)
                                    acc[dz][dy][dx] = fmaf(f[C + dx], wv, acc[dz][dy][dx]);
                            }
                        }
                    }
                }
            }
        }
        // shift-or pack (same f2b as before; final lo = even ch, hi = odd ch)
#pragma unroll
        for (int dz = 0; dz < 2; ++dz)
#pragma unroll
            for (int dy = 0; dy < 2; ++dy)
#pragma unroll
                for (int dx = 0; dx < 8; ++dx)
                    pk[dz][dy][dx] = (pk[dz][dy][dx] << 16) |
                                     (unsigned)(unsigned short)f2b(acc[dz][dy][dx]);
    }

    unsigned int* yb = yp + ((long)(b * 96 + chp) << 18);
#pragma unroll
    for (int dz = 0; dz < 2; ++dz)
#pragma unroll
        for (int dy = 0; dy < 2; ++dy) {
            unsigned int* op = yb + ((z0 + dz) << 12) + ((y0 + dy) << 6) + x0;
            uint4 o0, o1;
            o0.x = pk[dz][dy][0]; o0.y = pk[dz][dy][1];
            o0.z = pk[dz][dy][2]; o0.w = pk[dz][dy][3];
            o1.x = pk[dz][dy][4]; o1.y = pk[dz][dy][5];
            o1.z = pk[dz][dy][6]; o1.w = pk[dz][dy][7];
            *(uint4*)(op) = o0;
            *(uint4*)(op + 4) = o1;
        }
}

// ---------------------------------------------------------------------------
// K3: per-point 96->96 mix + bias as bf16 MFMA GEMM, reading PACKED bf16 y
// (rows 0..47 of out buffer) and writing f32 out (rows 0..95), same columns
// -> block-local overlap only, in-place safe.  (Verbatim R3 kernel: ~60 us.)
// ---------------------------------------------------------------------------
__global__ __launch_bounds__(256) void ek(float* __restrict__ io,
                                          const unsigned int* __restrict__ yp,
                                          const unsigned short* __restrict__ Mtt,
                                          const float* __restrict__ bias) {
    __shared__ float lds[96 * 128];             // 49152 B (stage uses first 24 KB)
    unsigned int* ldu = (unsigned int*)lds;
    const int t = threadIdx.x;
    const long row0 = (long)blockIdx.y * 96;
    const int pt0 = blockIdx.x << 7;            // this block's 128 pts

    // ---- stage 48 packed rows -> LDS (rotation-swizzled) -----------------
    {
        const int l32 = t & 31, r8 = t >> 5;
#pragma unroll
        for (int pass = 0; pass < 6; ++pass) {
            const int pr = r8 + (pass << 3);
            const uint4 v = *(const uint4*)(yp + ((row0 + pr) << 18) + pt0 + (l32 << 2));
            const int ws = (l32 + pr) & 31;
            *(uint4*)(ldu + (pr << 7) + (ws << 2)) = v;
        }
    }
    __syncthreads();

    const int lane = t & 63;
    const int wv4 = t >> 6;                    // wave id 0..3
    const int l15 = lane & 15, quad = lane >> 4;
    const int ptl = wv4 << 5;                  // wave's 32 pts within tile

    // B-frags: B[k=quad*8+j -> fv][n=l15 -> pt]; fv pair-rows 16ks+4q+jj
    bf16x8 Bf[2][3];
#pragma unroll
    for (int nt = 0; nt < 2; ++nt)
#pragma unroll
        for (int ks = 0; ks < 3; ++ks) {
            const int pt = ptl + nt * 16 + l15;
            const int pr0 = 16 * ks + 4 * quad;
            uint4 d;
            {
                const int b0 = (pt >> 2) + pr0;
                d.x = ldu[((pr0 + 0) << 7) + (((b0 + 0) & 31) << 2) + (pt & 3)];
                d.y = ldu[((pr0 + 1) << 7) + (((b0 + 1) & 31) << 2) + (pt & 3)];
                d.z = ldu[((pr0 + 2) << 7) + (((b0 + 2) & 31) << 2) + (pt & 3)];
                d.w = ldu[((pr0 + 3) << 7) + (((b0 + 3) & 31) << 2) + (pt & 3)];
            }
            Bf[nt][ks] = __builtin_bit_cast(bf16x8, d);
        }

    // A-frags (16B loads of bf16 Mtt, L1-resident) + MFMA; hold all C in regs
    float cv[6][2][4];
#pragma unroll
    for (int mt = 0; mt < 6; ++mt) {
        bf16x8 Af[3];
#pragma unroll
        for (int ks = 0; ks < 3; ++ks)
            Af[ks] = *(const bf16x8*)(Mtt + (mt * 16 + l15) * 96 + ks * 32 + quad * 8);
#pragma unroll
        for (int nt = 0; nt < 2; ++nt) {
            f32x4 c = {0.f, 0.f, 0.f, 0.f};
#pragma unroll
            for (int ks = 0; ks < 3; ++ks)
                c = __builtin_amdgcn_mfma_f32_16x16x32_bf16(Af[ks], Bf[nt][ks], c, 0, 0, 0);
#pragma unroll
            for (int r = 0; r < 4; ++r) cv[mt][nt][r] = c[r];
        }
    }
    __syncthreads();                            // all stage reads of LDS done

    // ---- transpose C through lds: row gw, rot 2*(gw>>2) ------------------
#pragma unroll
    for (int mt = 0; mt < 6; ++mt)
#pragma unroll
        for (int nt = 0; nt < 2; ++nt) {
            const int pt = ptl + nt * 16 + l15;
#pragma unroll
            for (int r = 0; r < 4; ++r) {
                const int gw = mt * 16 + quad * 4 + r;
                const int ws = ((pt >> 2) + 2 * (gw >> 2)) & 31;
                lds[(gw << 7) + (ws << 2) + (pt & 3)] = cv[mt][nt][r];
            }
        }
    __syncthreads();

    // ---- coalesced read-back + bias + dwordx4 stores ---------------------
    {
        const int l32 = t & 31, r8 = t >> 5;
#pragma unroll
        for (int pass = 0; pass < 12; ++pass) {
            const int row = r8 + (pass << 3);
            const int ws = (l32 + 2 * (row >> 2)) & 31;
            float4 v = *(const float4*)(lds + (row << 7) + (ws << 2));
            const float bs = bias[row / 12];
            v.x += bs; v.y += bs; v.z += bs; v.w += bs;
            *(float4*)(io + ((row0 + row) << 18) + pt0 + (l32 << 2)) = v;
        }
    }
}

// ---------------------------------------------------------------------------
extern "C" void kernel_launch(void* const* d_in, const int* in_sizes, int n_in,
                              void* d_out, int out_size, void* d_ws, size_t ws_size,
                              hipStream_t stream) {
    const float* x        = (const float*)d_in[0];
    const float* spatial  = (const float*)d_in[1];
    const float* spherical= (const float*)d_in[2];
    const float* bw1 = (const float*)d_in[3];
    const float* bb1 = (const float*)d_in[4];
    const float* bw2 = (const float*)d_in[5];
    const float* bb2 = (const float*)d_in[6];
    const float* bw3 = (const float*)d_in[7];
    const float* fw1 = (const float*)d_in[8];
    const float* fb1 = (const float*)d_in[9];
    const float* fw2 = (const float*)d_in[10];
    const float* fb2 = (const float*)d_in[11];
    const float* fw3 = (const float*)d_in[12];
    const float* bias = (const float*)d_in[13];

    float* sw = (float*)d_ws;                                     // 12000 floats
    unsigned short* Mtt = (unsigned short*)((char*)d_ws + 48128); // 9216 bf16
    float* out = (float*)d_out;          // rows 0..47: packed bf16 y staging

    hipLaunchKernelGGL(wk, dim3(7), dim3(256), 0, stream,
                       spatial, spherical, bw1, bb1, bw2, bb2, bw3,
                       fw1, fb1, fw2, fb2, fw3, sw, Mtt);
    hipLaunchKernelGGL(ck, dim3(32, 48, 2), dim3(256), 0, stream,
                       x, sw, (unsigned int*)out);
    hipLaunchKernelGGL(ek, dim3(2048, 2, 1), dim3(256), 0, stream,
                       out, (const unsigned int*)out, Mtt, bias);
    (void)in_sizes; (void)n_in; (void)out_size; (void)ws_size;
}